// Round 1
// baseline (451.194 us; speedup 1.0000x reference)
//
#include <hip/hip_runtime.h>

// Problem constants (fixed by the reference)
constexpr int Bc  = 4;
constexpr int Lc  = 2048;
constexpr int Dc  = 8192;
constexpr int QKc = 2048;
constexpr int Vc  = 4096;
constexpr int TCH = 32;          // timesteps per thread (32 -> 524,288 threads = 100% of device capacity)
constexpr int NCH = Lc / TCH;    // 64 chunks
constexpr int D4  = Dc / 4;      // 2048 float4 channel groups

// Output layout offsets in float4 units: q | k | v | new_cache
constexpr size_t K_OFF4 = (size_t)Bc * Lc * QKc / 4;            // 4,194,304
constexpr size_t V_OFF4 = 2 * K_OFF4;                           // 8,388,608
constexpr size_t C_OFF4 = V_OFF4 + (size_t)Bc * Lc * Vc / 4;    // 16,777,216

// Native clang vector type so __builtin_nontemporal_{load,store} accept it
using f32x4 = __attribute__((ext_vector_type(4))) float;

__device__ __forceinline__ float silu_fast(float v) {
    // v * rcp(1+exp(-v)): v_rcp_f32 is ~1 ulp, well inside the 2e-3 tolerance,
    // and replaces the ~12-op precise-division sequence with 1 instruction.
    return v * __builtin_amdgcn_rcpf(1.0f + __expf(-v));
}

__global__ __launch_bounds__(256)
void qkvconv_kernel(const f32x4* __restrict__ x4,
                    const f32x4* __restrict__ cache4,
                    const f32x4* __restrict__ w4,
                    f32x4* __restrict__ out4)
{
    const int gid   = blockIdx.x * blockDim.x + threadIdx.x;
    const int dg    = gid & (D4 - 1);      // float4 channel group
    const int rest  = gid >> 11;           // D4 == 2^11
    const int chunk = rest & (NCH - 1);
    const int b     = rest >> 6;           // NCH == 2^6

    const int d  = dg << 2;                // first channel of this thread
    const int t0 = chunk * TCH;

    // weight rows are naturally float4 (K=4): wr_i = taps for channel d+i
    const f32x4 wr0 = w4[d + 0];
    const f32x4 wr1 = w4[d + 1];
    const f32x4 wr2 = w4[d + 2];
    const f32x4 wr3 = w4[d + 3];

    const size_t xbase = ((size_t)b * Lc) * D4 + dg;

    // rolling history: h0 = x[t-3], h1 = x[t-2], h2 = x[t-1] (per channel)
    f32x4 h0, h1, h2;
    if (t0 == 0) {
        // cache row per channel is float4; taps 1..3 are the causal history
        const f32x4 c0 = cache4[(size_t)b * Dc + d + 0];
        const f32x4 c1 = cache4[(size_t)b * Dc + d + 1];
        const f32x4 c2 = cache4[(size_t)b * Dc + d + 2];
        const f32x4 c3 = cache4[(size_t)b * Dc + d + 3];
        h0 = (f32x4){c0.y, c1.y, c2.y, c3.y};
        h1 = (f32x4){c0.z, c1.z, c2.z, c3.z};
        h2 = (f32x4){c0.w, c1.w, c2.w, c3.w};
    } else {
        h0 = __builtin_nontemporal_load(&x4[xbase + (size_t)(t0 - 3) * D4]);
        h1 = __builtin_nontemporal_load(&x4[xbase + (size_t)(t0 - 2) * D4]);
        h2 = __builtin_nontemporal_load(&x4[xbase + (size_t)(t0 - 1) * D4]);
    }

    // output base (float4 units) + per-timestep stride, by q/k/v segment
    size_t obase;
    int    ostride;
    if (d < QKc) {
        obase   = ((size_t)b * Lc) * (QKc / 4) + dg;
        ostride = QKc / 4;
    } else if (d < 2 * QKc) {
        obase   = K_OFF4 + ((size_t)b * Lc) * (QKc / 4) + (dg - QKc / 4);
        ostride = QKc / 4;
    } else {
        obase   = V_OFF4 + ((size_t)b * Lc) * (Vc / 4) + (dg - 2 * QKc / 4);
        ostride = Vc / 4;
    }

    #pragma unroll 4
    for (int t = t0; t < t0 + TCH; ++t) {
        const f32x4 cur = __builtin_nontemporal_load(&x4[xbase + (size_t)t * D4]);
        f32x4 y;
        y.x = wr0.x * h0.x + wr0.y * h1.x + wr0.z * h2.x + wr0.w * cur.x;
        y.y = wr1.x * h0.y + wr1.y * h1.y + wr1.z * h2.y + wr1.w * cur.y;
        y.z = wr2.x * h0.z + wr2.y * h1.z + wr2.z * h2.z + wr2.w * cur.z;
        y.w = wr3.x * h0.w + wr3.y * h1.w + wr3.z * h2.w + wr3.w * cur.w;
        y.x = silu_fast(y.x);
        y.y = silu_fast(y.y);
        y.z = silu_fast(y.z);
        y.w = silu_fast(y.w);
        __builtin_nontemporal_store(y, &out4[obase + (size_t)t * ostride]);
        h0 = h1; h1 = h2; h2 = cur;
    }

    // last chunk writes new_cache[b, d, 0..3] = x[b, L-4 .. L-1, d]
    if (chunk == NCH - 1) {
        const f32x4 xm4 =
            __builtin_nontemporal_load(&x4[xbase + (size_t)(Lc - 4) * D4]);
        // after loop: h0 = x[L-3], h1 = x[L-2], h2 = x[L-1]
        out4[C_OFF4 + (size_t)b * Dc + d + 0] = (f32x4){xm4.x, h0.x, h1.x, h2.x};
        out4[C_OFF4 + (size_t)b * Dc + d + 1] = (f32x4){xm4.y, h0.y, h1.y, h2.y};
        out4[C_OFF4 + (size_t)b * Dc + d + 2] = (f32x4){xm4.z, h0.z, h1.z, h2.z};
        out4[C_OFF4 + (size_t)b * Dc + d + 3] = (f32x4){xm4.w, h0.w, h1.w, h2.w};
    }
}

extern "C" void kernel_launch(void* const* d_in, const int* in_sizes, int n_in,
                              void* d_out, int out_size, void* d_ws, size_t ws_size,
                              hipStream_t stream) {
    const f32x4* x4     = (const f32x4*)d_in[0];   // (B, L, D) fp32
    const f32x4* cache4 = (const f32x4*)d_in[1];   // (B, D, K) fp32
    const f32x4* w4     = (const f32x4*)d_in[2];   // (D, K) fp32
    f32x4* out4 = (f32x4*)d_out;                   // q|k|v|new_cache fp32

    const int total  = Bc * NCH * D4;              // 524,288 threads
    const int block  = 256;
    qkvconv_kernel<<<total / block, block, 0, stream>>>(x4, cache4, w4, out4);
}